// Round 1
// baseline (148.249 us; speedup 1.0000x reference)
//
#include <hip/hip_runtime.h>
#include <hip/hip_bf16.h>

#define BS 8
#define SEQ 512
#define DKDIM 2048

using bf16x8 = __attribute__((ext_vector_type(8))) __bf16;
using f32x4  = __attribute__((ext_vector_type(4))) float;

__device__ __forceinline__ unsigned short f2bf(float f) {
    unsigned int u = __builtin_bit_cast(unsigned int, f);
    u += 0x7FFFu + ((u >> 16) & 1u);
    return (unsigned short)(u >> 16);
}
__device__ __forceinline__ float bf2f(unsigned short h) {
    unsigned int u = ((unsigned int)h) << 16;
    return __builtin_bit_cast(float, u);
}

__device__ __forceinline__ void gload_lds16(const unsigned short* g, unsigned short* l) {
    __builtin_amdgcn_global_load_lds(
        (const __attribute__((address_space(1))) unsigned int*)g,
        (__attribute__((address_space(3))) unsigned int*)l, 16, 0, 0);
}

// ---------------------------------------------------------------------------
// Transpose+convert: in [SEQ][DK] f32 (per batch) -> out [DK][SEQ] bf16
// z < BS: q batch z ; z >= BS: k batch z-BS
// ---------------------------------------------------------------------------
__global__ __launch_bounds__(256) void transpose_conv_kernel(
    const float* __restrict__ q, const float* __restrict__ k,
    unsigned short* __restrict__ qT, unsigned short* __restrict__ kT)
{
    int z = blockIdx.z;
    const float* in = (z < BS) ? q : k;
    unsigned short* out = (z < BS) ? qT : kT;
    int b = z & (BS - 1);
    in  += (size_t)b * SEQ * DKDIM;
    out += (size_t)b * DKDIM * SEQ;
    int s0 = blockIdx.y * 64;
    int d0 = blockIdx.x * 64;
    __shared__ unsigned short tile[64][66];
    int t = threadIdx.x;
    int tr  = t >> 4;         // 0..15
    int tc4 = (t & 15) * 4;   // 0..60
    #pragma unroll
    for (int p = 0; p < 4; ++p) {
        int s = p * 16 + tr;
        float4 v4 = *reinterpret_cast<const float4*>(&in[(size_t)(s0 + s) * DKDIM + d0 + tc4]);
        tile[s][tc4 + 0] = f2bf(v4.x);
        tile[s][tc4 + 1] = f2bf(v4.y);
        tile[s][tc4 + 2] = f2bf(v4.z);
        tile[s][tc4 + 3] = f2bf(v4.w);
    }
    __syncthreads();
    #pragma unroll
    for (int p = 0; p < 4; ++p) {
        int d = p * 16 + tr;
        ushort4 o;
        o.x = tile[tc4 + 0][d];
        o.y = tile[tc4 + 1][d];
        o.z = tile[tc4 + 2][d];
        o.w = tile[tc4 + 3][d];
        *reinterpret_cast<ushort4*>(&out[(size_t)(d0 + d) * SEQ + s0 + tc4]) = o;
    }
}

// ---------------------------------------------------------------------------
// GEMM C = A * B^T : A [M][K] bf16, B [N][K] bf16, both row-major (K inner).
// DO_EXP=1: C is bf16, element = exp(scale * acc)   (fused softmax numerator)
// DO_EXP=0: C is f32,  element = acc
// BM=BN=128, BK=64, 256 threads = 4 waves in 2x2, wave tile 64x64 (4x4 frags)
// ---------------------------------------------------------------------------
template<int DO_EXP>
__global__ __launch_bounds__(256) void gemm_bt_kernel(
    const unsigned short* __restrict__ A,
    const unsigned short* __restrict__ B,
    void* __restrict__ C,
    int M, int N, int K,
    long Abs, long Bbs, long Cbs,
    float scale)
{
    int b = blockIdx.z;
    A += (size_t)b * Abs;
    B += (size_t)b * Bbs;
    int m0 = blockIdx.y * 128;
    int n0 = blockIdx.x * 128;

    __shared__ unsigned short lA[128 * 64];
    __shared__ unsigned short lB[128 * 64];

    int t = threadIdx.x;
    int w = t >> 6, l = t & 63;
    int wm = w >> 1, wn = w & 1;

    f32x4 acc[4][4] = {};

    int srow = (l >> 3);        // 0..7
    int scol = (l & 7) * 8;     // 0..56 (ushorts)

    for (int k0 = 0; k0 < K; k0 += 64) {
        #pragma unroll
        for (int rnd = 0; rnd < 4; ++rnd) {
            int row = rnd * 32 + w * 8 + srow;
            const unsigned short* ga = A + (size_t)(m0 + row) * K + k0 + scol;
            const unsigned short* gb = B + (size_t)(n0 + row) * K + k0 + scol;
            gload_lds16(ga, &lA[row * 64 + scol]);
            gload_lds16(gb, &lB[row * 64 + scol]);
        }
        __syncthreads();
        #pragma unroll
        for (int ks = 0; ks < 2; ++ks) {
            bf16x8 af[4], bfr[4];
            #pragma unroll
            for (int f = 0; f < 4; ++f) {
                int arow = wm * 64 + f * 16 + (l & 15);
                int koff = ks * 32 + (l >> 4) * 8;
                af[f]  = *reinterpret_cast<const bf16x8*>(&lA[arow * 64 + koff]);
                int brow = wn * 64 + f * 16 + (l & 15);
                bfr[f] = *reinterpret_cast<const bf16x8*>(&lB[brow * 64 + koff]);
            }
            #pragma unroll
            for (int i = 0; i < 4; ++i)
                #pragma unroll
                for (int j = 0; j < 4; ++j)
                    acc[i][j] = __builtin_amdgcn_mfma_f32_16x16x32_bf16(af[i], bfr[j], acc[i][j], 0, 0, 0);
        }
        __syncthreads();
    }

    int crow_base = m0 + wm * 64 + (l >> 4) * 4;
    int ccol_base = n0 + wn * 64 + (l & 15);
    if (DO_EXP) {
        unsigned short* E = (unsigned short*)C + (size_t)b * Cbs;
        #pragma unroll
        for (int i = 0; i < 4; ++i)
            #pragma unroll
            for (int j = 0; j < 4; ++j)
                #pragma unroll
                for (int r = 0; r < 4; ++r) {
                    int row = crow_base + i * 16 + r;
                    int col = ccol_base + j * 16;
                    E[(size_t)row * N + col] = f2bf(__expf(scale * acc[i][j][r]));
                }
    } else {
        float* Cf = (float*)C + (size_t)b * Cbs;
        #pragma unroll
        for (int i = 0; i < 4; ++i)
            #pragma unroll
            for (int j = 0; j < 4; ++j)
                #pragma unroll
                for (int r = 0; r < 4; ++r) {
                    int row = crow_base + i * 16 + r;
                    int col = ccol_base + j * 16;
                    Cf[(size_t)row * N + col] = acc[i][j][r];
                }
    }
}

// ---------------------------------------------------------------------------
// Column partial sums of E over d-chunks: rpart[dc][b][e] = sum_{d in chunk} E[b][d][e]
// block: 256 threads, 2 columns/thread (ushort2 reads), 256 rows
// grid: (DK/512, 8 d-chunks, BS)
// ---------------------------------------------------------------------------
__global__ __launch_bounds__(256) void colsum_kernel(
    const unsigned short* __restrict__ E, float* __restrict__ rpart)
{
    int e0 = blockIdx.x * 512 + threadIdx.x * 2;
    int dc = blockIdx.y, b = blockIdx.z;
    const unsigned short* Eb = E + (size_t)b * DKDIM * DKDIM + (size_t)dc * 256 * DKDIM + e0;
    float s0 = 0.f, s1 = 0.f;
    for (int d = 0; d < 256; ++d) {
        unsigned int u = *reinterpret_cast<const unsigned int*>(Eb + (size_t)d * DKDIM);
        s0 += bf2f((unsigned short)(u & 0xffffu));
        s1 += bf2f((unsigned short)(u >> 16));
    }
    float* rp = rpart + ((size_t)dc * BS + b) * DKDIM;
    rp[e0] = s0;
    rp[e0 + 1] = s1;
}

__global__ __launch_bounds__(256) void colsum_finish(
    const float* __restrict__ rpart, float* __restrict__ rinv)
{
    int i = blockIdx.x * 256 + threadIdx.x;   // i = b*DK + e, total BS*DK
    float s = 0.f;
    #pragma unroll
    for (int dc = 0; dc < 8; ++dc) s += rpart[(size_t)dc * BS * DKDIM + i];
    rinv[i] = 1.0f / s;
}

// ---------------------------------------------------------------------------
// v'[b][s][e] = bf16( v[b][s][e] * rinv[b][e] )
// ---------------------------------------------------------------------------
__global__ __launch_bounds__(256) void vprime_kernel(
    const float* __restrict__ v, const float* __restrict__ rinv,
    unsigned short* __restrict__ vp)
{
    size_t i4 = ((size_t)blockIdx.x * 256 + threadIdx.x) * 4;
    int e = (int)(i4 & (DKDIM - 1));
    int b = (int)(i4 >> 20);             // SEQ*DK = 2^20
    float4 v4 = *reinterpret_cast<const float4*>(&v[i4]);
    float4 r4 = *reinterpret_cast<const float4*>(&rinv[(size_t)b * DKDIM + e]);
    ushort4 o;
    o.x = f2bf(v4.x * r4.x);
    o.y = f2bf(v4.y * r4.y);
    o.z = f2bf(v4.z * r4.z);
    o.w = f2bf(v4.w * r4.w);
    *reinterpret_cast<ushort4*>(&vp[i4]) = o;
}

extern "C" void kernel_launch(void* const* d_in, const int* in_sizes, int n_in,
                              void* d_out, int out_size, void* d_ws, size_t ws_size,
                              hipStream_t stream) {
    const float* q = (const float*)d_in[0];
    const float* k = (const float*)d_in[1];
    const float* v = (const float*)d_in[2];
    float* out = (float*)d_out;

    char* ws = (char*)d_ws;
    unsigned short* qT = (unsigned short*)(ws);                        // 16 MB
    unsigned short* kT = (unsigned short*)(ws + 16777216);             // 16 MB
    unsigned short* E  = (unsigned short*)(ws + 33554432);             // 64 MB
    float* rpart       = (float*)(ws + 100663296);                     // 512 KB
    float* rinv        = (float*)(ws + 101187584);                     // 64 KB
    unsigned short* vp = (unsigned short*)(ws + 101253120);            // 16 MB

    const float scale = 0.022097086912079608f;  // 1/sqrt(2048)

    // q,k -> [d][s] bf16
    transpose_conv_kernel<<<dim3(DKDIM / 64, SEQ / 64, 2 * BS), 256, 0, stream>>>(q, k, qT, kT);

    // E[b][d][e] = exp(scale * sum_s qT[d][s] kT[e][s])   (bf16)
    gemm_bt_kernel<1><<<dim3(DKDIM / 128, DKDIM / 128, BS), 256, 0, stream>>>(
        qT, kT, (void*)E, DKDIM, DKDIM, SEQ,
        (long)DKDIM * SEQ, (long)DKDIM * SEQ, (long)DKDIM * DKDIM, scale);

    // column sums over d  ->  rinv[b][e] = 1/sum
    colsum_kernel<<<dim3(DKDIM / 512, 8, BS), 256, 0, stream>>>(E, rpart);
    colsum_finish<<<dim3(BS * DKDIM / 256), 256, 0, stream>>>(rpart, rinv);

    // v' = v * rinv (bf16)
    vprime_kernel<<<dim3(BS * SEQ * DKDIM / 1024), 256, 0, stream>>>(v, rinv, vp);

    // out[b][s][d] = sum_e v'[s][e] * E[d][e]   (f32)
    gemm_bt_kernel<0><<<dim3(DKDIM / 128, SEQ / 128, BS), 256, 0, stream>>>(
        vp, E, (void*)out, SEQ, DKDIM, DKDIM,
        (long)SEQ * DKDIM, (long)DKDIM * DKDIM, (long)SEQ * DKDIM, 1.0f);
}

// Round 2
// 147.867 us; speedup vs baseline: 1.0026x; 1.0026x over previous
//
#include <hip/hip_runtime.h>
#include <hip/hip_bf16.h>

#define BS 8
#define SEQ 512
#define DKDIM 2048

using bf16x8 = __attribute__((ext_vector_type(8))) __bf16;
using f32x4  = __attribute__((ext_vector_type(4))) float;

__device__ __forceinline__ unsigned short f2bf(float f) {
    unsigned int u = __builtin_bit_cast(unsigned int, f);
    u += 0x7FFFu + ((u >> 16) & 1u);
    return (unsigned short)(u >> 16);
}
__device__ __forceinline__ float bf2f(unsigned short h) {
    unsigned int u = ((unsigned int)h) << 16;
    return __builtin_bit_cast(float, u);
}

__device__ __forceinline__ void gload_lds16(const unsigned short* g, unsigned short* l) {
    __builtin_amdgcn_global_load_lds(
        (const __attribute__((address_space(1))) unsigned int*)g,
        (__attribute__((address_space(3))) unsigned int*)l, 16, 0, 0);
}

// ---------------------------------------------------------------------------
// Transpose+convert: in [SEQ][DK] f32 (per batch) -> out [DK][SEQ] bf16
// z < BS: q batch z ; z >= BS: k batch z-BS
// ---------------------------------------------------------------------------
__global__ __launch_bounds__(256) void transpose_conv_kernel(
    const float* __restrict__ q, const float* __restrict__ k,
    unsigned short* __restrict__ qT, unsigned short* __restrict__ kT)
{
    int z = blockIdx.z;
    const float* in = (z < BS) ? q : k;
    unsigned short* out = (z < BS) ? qT : kT;
    int b = z & (BS - 1);
    in  += (size_t)b * SEQ * DKDIM;
    out += (size_t)b * DKDIM * SEQ;
    int s0 = blockIdx.y * 64;
    int d0 = blockIdx.x * 64;
    __shared__ unsigned short tile[64][66];
    int t = threadIdx.x;
    int tr  = t >> 4;         // 0..15
    int tc4 = (t & 15) * 4;   // 0..60
    #pragma unroll
    for (int p = 0; p < 4; ++p) {
        int s = p * 16 + tr;
        float4 v4 = *reinterpret_cast<const float4*>(&in[(size_t)(s0 + s) * DKDIM + d0 + tc4]);
        tile[s][tc4 + 0] = f2bf(v4.x);
        tile[s][tc4 + 1] = f2bf(v4.y);
        tile[s][tc4 + 2] = f2bf(v4.z);
        tile[s][tc4 + 3] = f2bf(v4.w);
    }
    __syncthreads();
    #pragma unroll
    for (int p = 0; p < 4; ++p) {
        int d = p * 16 + tr;
        ushort4 o;
        o.x = tile[tc4 + 0][d];
        o.y = tile[tc4 + 1][d];
        o.z = tile[tc4 + 2][d];
        o.w = tile[tc4 + 3][d];
        *reinterpret_cast<ushort4*>(&out[(size_t)(d0 + d) * SEQ + s0 + tc4]) = o;
    }
}

// ---------------------------------------------------------------------------
// GEMM C = A * B^T : A [M][K] bf16, B [N][K] bf16, both row-major (K inner).
// MFMA operands are SWAPPED (mfma(b,a,acc)) so each lane holds 4 consecutive
// n-dim elements per fragment: m = m0+wm*64+i*16+(l&15),
// n = n0+wn*64+j*16+(l>>4)*4+r  -> packed epilogue stores.
// DO_EXP=1: C bf16 = exp(scale*acc); also writes per-(mtile,wavehalf) column
//           partial sums to rpart[(mt*2+wm)][b][n]  (softmax denominator).
// DO_EXP=0: C f32 = acc, float4 stores.
// BM=BN=128, BK=64, 256 threads = 4 waves in 2x2, wave tile 64x64 (4x4 frags)
// ---------------------------------------------------------------------------
template<int DO_EXP>
__global__ __launch_bounds__(256) void gemm_bt_kernel(
    const unsigned short* __restrict__ A,
    const unsigned short* __restrict__ B,
    void* __restrict__ C,
    float* __restrict__ rpart,
    int M, int N, int K,
    long Abs, long Bbs, long Cbs,
    float scale)
{
    int b = blockIdx.z;
    A += (size_t)b * Abs;
    B += (size_t)b * Bbs;
    int m0 = blockIdx.y * 128;
    int n0 = blockIdx.x * 128;

    __shared__ unsigned short lA[128 * 64];
    __shared__ unsigned short lB[128 * 64];

    int t = threadIdx.x;
    int w = t >> 6, l = t & 63;
    int wm = w >> 1, wn = w & 1;

    f32x4 acc[4][4] = {};

    int srow = (l >> 3);        // 0..7
    int scol = (l & 7) * 8;     // 0..56 (ushorts)

    for (int k0 = 0; k0 < K; k0 += 64) {
        #pragma unroll
        for (int rnd = 0; rnd < 4; ++rnd) {
            int row = rnd * 32 + w * 8 + srow;
            const unsigned short* ga = A + (size_t)(m0 + row) * K + k0 + scol;
            const unsigned short* gb = B + (size_t)(n0 + row) * K + k0 + scol;
            gload_lds16(ga, &lA[row * 64 + scol]);
            gload_lds16(gb, &lB[row * 64 + scol]);
        }
        __syncthreads();
        #pragma unroll
        for (int ks = 0; ks < 2; ++ks) {
            bf16x8 af[4], bfr[4];
            #pragma unroll
            for (int f = 0; f < 4; ++f) {
                int arow = wm * 64 + f * 16 + (l & 15);
                int koff = ks * 32 + (l >> 4) * 8;
                af[f]  = *reinterpret_cast<const bf16x8*>(&lA[arow * 64 + koff]);
                int brow = wn * 64 + f * 16 + (l & 15);
                bfr[f] = *reinterpret_cast<const bf16x8*>(&lB[brow * 64 + koff]);
            }
            #pragma unroll
            for (int i = 0; i < 4; ++i)
                #pragma unroll
                for (int j = 0; j < 4; ++j)
                    acc[i][j] = __builtin_amdgcn_mfma_f32_16x16x32_bf16(bfr[j], af[i], acc[i][j], 0, 0, 0);
        }
        __syncthreads();
    }

    int mbase = m0 + wm * 64 + (l & 15);        // + i*16
    int nbase = n0 + wn * 64 + (l >> 4) * 4;    // + j*16  (+r consecutive)

    if (DO_EXP) {
        unsigned short* Eo = (unsigned short*)C + (size_t)b * Cbs;
        float csum[16];
        #pragma unroll
        for (int x = 0; x < 16; ++x) csum[x] = 0.f;
        #pragma unroll
        for (int i = 0; i < 4; ++i) {
            #pragma unroll
            for (int j = 0; j < 4; ++j) {
                float e0 = __expf(scale * acc[i][j][0]);
                float e1 = __expf(scale * acc[i][j][1]);
                float e2 = __expf(scale * acc[i][j][2]);
                float e3 = __expf(scale * acc[i][j][3]);
                csum[j * 4 + 0] += e0;
                csum[j * 4 + 1] += e1;
                csum[j * 4 + 2] += e2;
                csum[j * 4 + 3] += e3;
                ushort4 o;
                o.x = f2bf(e0); o.y = f2bf(e1); o.z = f2bf(e2); o.w = f2bf(e3);
                *reinterpret_cast<ushort4*>(&Eo[(size_t)(mbase + i * 16) * N + nbase + j * 16]) = o;
            }
        }
        // reduce each csum over the 16 m-lanes (xor bits 0..3): sum over this
        // wave's 64 m-rows (i-frags already accumulated in-register)
        #pragma unroll
        for (int x = 0; x < 16; ++x) {
            float s = csum[x];
            s += __shfl_xor(s, 1, 64);
            s += __shfl_xor(s, 2, 64);
            s += __shfl_xor(s, 4, 64);
            s += __shfl_xor(s, 8, 64);
            csum[x] = s;
        }
        // lane (l&15)==x contributes csum[x]; its n-coord: j=x>>2, r=x&3, g=l>>4
        int m = l & 15, g = l >> 4;
        float val = 0.f;
        #pragma unroll
        for (int x = 0; x < 16; ++x)
            if (m == x) val = csum[x];   // compile-time indexed, predicated
        int e = n0 + wn * 64 + (m >> 2) * 16 + g * 4 + (m & 3);
        rpart[((size_t)(blockIdx.y * 2 + wm) * BS + b) * (size_t)N + e] = val;
    } else {
        float* Cf = (float*)C + (size_t)b * Cbs;
        #pragma unroll
        for (int i = 0; i < 4; ++i)
            #pragma unroll
            for (int j = 0; j < 4; ++j)
                *reinterpret_cast<f32x4*>(&Cf[(size_t)(mbase + i * 16) * N + nbase + j * 16]) = acc[i][j];
    }
}

// ---------------------------------------------------------------------------
// rinv[b][e] = 1 / sum over 32 partials (16 m-tiles x 2 wave-halves)
// ---------------------------------------------------------------------------
__global__ __launch_bounds__(256) void colsum_finish(
    const float* __restrict__ rpart, float* __restrict__ rinv)
{
    int i = blockIdx.x * 256 + threadIdx.x;   // i = b*DK + e, total BS*DK
    float s = 0.f;
    #pragma unroll
    for (int p = 0; p < 32; ++p) s += rpart[(size_t)p * BS * DKDIM + i];
    rinv[i] = 1.0f / s;
}

// ---------------------------------------------------------------------------
// v'[b][s][e] = bf16( v[b][s][e] * rinv[b][e] )
// ---------------------------------------------------------------------------
__global__ __launch_bounds__(256) void vprime_kernel(
    const float* __restrict__ v, const float* __restrict__ rinv,
    unsigned short* __restrict__ vp)
{
    size_t i4 = ((size_t)blockIdx.x * 256 + threadIdx.x) * 4;
    int e = (int)(i4 & (DKDIM - 1));
    int b = (int)(i4 >> 20);             // SEQ*DK = 2^20
    float4 v4 = *reinterpret_cast<const float4*>(&v[i4]);
    float4 r4 = *reinterpret_cast<const float4*>(&rinv[(size_t)b * DKDIM + e]);
    ushort4 o;
    o.x = f2bf(v4.x * r4.x);
    o.y = f2bf(v4.y * r4.y);
    o.z = f2bf(v4.z * r4.z);
    o.w = f2bf(v4.w * r4.w);
    *reinterpret_cast<ushort4*>(&vp[i4]) = o;
}

extern "C" void kernel_launch(void* const* d_in, const int* in_sizes, int n_in,
                              void* d_out, int out_size, void* d_ws, size_t ws_size,
                              hipStream_t stream) {
    const float* q = (const float*)d_in[0];
    const float* k = (const float*)d_in[1];
    const float* v = (const float*)d_in[2];
    float* out = (float*)d_out;

    char* ws = (char*)d_ws;
    unsigned short* qT = (unsigned short*)(ws);                        // 16 MB
    unsigned short* kT = (unsigned short*)(ws + 16777216);             // 16 MB
    unsigned short* E  = (unsigned short*)(ws + 33554432);             // 64 MB
    float* rpart       = (float*)(ws + 100663296);                     // 2 MB  (32 x 8 x 2048 f32)
    float* rinv        = (float*)(ws + 102760448);                     // 64 KB
    unsigned short* vp = (unsigned short*)(ws + 103809024);            // 16 MB

    const float scale = 0.022097086912079608f;  // 1/sqrt(2048)

    // q,k -> [d][s] bf16
    transpose_conv_kernel<<<dim3(DKDIM / 64, SEQ / 64, 2 * BS), 256, 0, stream>>>(q, k, qT, kT);

    // E[b][d][e] = exp(scale * sum_s qT[d][s] kT[e][s])  (bf16) + column partials
    gemm_bt_kernel<1><<<dim3(DKDIM / 128, DKDIM / 128, BS), 256, 0, stream>>>(
        qT, kT, (void*)E, rpart, DKDIM, DKDIM, SEQ,
        (long)DKDIM * SEQ, (long)DKDIM * SEQ, (long)DKDIM * DKDIM, scale);

    // rinv[b][e] = 1/colsum
    colsum_finish<<<dim3(BS * DKDIM / 256), 256, 0, stream>>>(rpart, rinv);

    // v' = v * rinv (bf16)
    vprime_kernel<<<dim3(BS * SEQ * DKDIM / 1024), 256, 0, stream>>>(v, rinv, vp);

    // out[b][s][d] = sum_e v'[s][e] * E[d][e]   (f32)
    gemm_bt_kernel<0><<<dim3(DKDIM / 128, SEQ / 128, BS), 256, 0, stream>>>(
        vp, E, (void*)out, nullptr, SEQ, DKDIM, DKDIM,
        (long)SEQ * DKDIM, (long)DKDIM * DKDIM, (long)SEQ * DKDIM, 1.0f);
}

// Round 4
// 135.088 us; speedup vs baseline: 1.0974x; 1.0946x over previous
//
#include <hip/hip_runtime.h>
#include <hip/hip_bf16.h>

#define BS 8
#define SEQ 512
#define DKDIM 2048

using bf16x8 = __attribute__((ext_vector_type(8))) __bf16;
using f32x4  = __attribute__((ext_vector_type(4))) float;

__device__ __forceinline__ unsigned short f2bf(float f) {
    unsigned int u = __builtin_bit_cast(unsigned int, f);
    u += 0x7FFFu + ((u >> 16) & 1u);
    return (unsigned short)(u >> 16);
}

__device__ __forceinline__ void gload_lds16(const unsigned short* g, unsigned short* l) {
    __builtin_amdgcn_global_load_lds(
        (const __attribute__((address_space(1))) unsigned int*)g,
        (__attribute__((address_space(3))) unsigned int*)l, 16, 0, 0);
}

#define PH_BARRIER() asm volatile("s_barrier" ::: "memory")

// ---------------------------------------------------------------------------
// Transpose+convert: in [SEQ][DK] f32 (per batch) -> out [DK][SEQ] bf16
// ---------------------------------------------------------------------------
__global__ __launch_bounds__(256) void transpose_conv_kernel(
    const float* __restrict__ q, const float* __restrict__ k,
    unsigned short* __restrict__ qT, unsigned short* __restrict__ kT)
{
    int z = blockIdx.z;
    const float* in = (z < BS) ? q : k;
    unsigned short* out = (z < BS) ? qT : kT;
    int b = z & (BS - 1);
    in  += (size_t)b * SEQ * DKDIM;
    out += (size_t)b * DKDIM * SEQ;
    int s0 = blockIdx.y * 64;
    int d0 = blockIdx.x * 64;
    __shared__ unsigned short tile[64][66];
    int t = threadIdx.x;
    int tr  = t >> 4;
    int tc4 = (t & 15) * 4;
    #pragma unroll
    for (int p = 0; p < 4; ++p) {
        int s = p * 16 + tr;
        float4 v4 = *reinterpret_cast<const float4*>(&in[(size_t)(s0 + s) * DKDIM + d0 + tc4]);
        tile[s][tc4 + 0] = f2bf(v4.x);
        tile[s][tc4 + 1] = f2bf(v4.y);
        tile[s][tc4 + 2] = f2bf(v4.z);
        tile[s][tc4 + 3] = f2bf(v4.w);
    }
    __syncthreads();
    #pragma unroll
    for (int p = 0; p < 4; ++p) {
        int d = p * 16 + tr;
        ushort4 o;
        o.x = tile[tc4 + 0][d];
        o.y = tile[tc4 + 1][d];
        o.z = tile[tc4 + 2][d];
        o.w = tile[tc4 + 3][d];
        *reinterpret_cast<ushort4*>(&out[(size_t)(d0 + d) * SEQ + s0 + tc4]) = o;
    }
}

// ---------------------------------------------------------------------------
// GEMM1: E[b][d][e] = exp(scale * sum_s qT[d][s]*kT[e][s]), bf16 out, plus
// per-(mtile,wavehalf) column partial sums -> rpart.
// 256x256 tile, BK=64, 8 waves (2M x 4N), wave tile 128x64, 4 phases/K-tile.
//
// STAGE HALVES ARE READ-GROUP-MATCHED (fix of the r3 race):
//   A-half h = rows with (row&64)==h*64  (a0 group reads h=0, a1 reads h=1)
//   B-half h = rows with (row&32)==h*32  (b0 reads h=0, b1 reads h=1)
// Schedule per K-tile tt (buf = tt&1), quadrants q00,q01,q11,q10:
//   ph0: rd a0(8)+b0(4); stage (tt+1).A1 -> buf^1 | bar lgk0 prio1 16MFMA prio0 bar
//   ph1: rd b1(4);       stage (tt+2).A0 -> buf   | ...
//   ph2: rd a1(8);       stage (tt+2).B0 -> buf   | ...
//   ph3: regs held;      stage (tt+2).B1 -> buf   | bar prio1 16MFMA prio0 vmcnt bar
// Liveness: each staged half was last ds_read in a phase whose lgkmcnt(0)
// + closing barrier precede the staging phase. Tile-end vmcnt(6) leaves
// exactly tile(tt+2)'s {A0,B0,B1} in flight => tile tt+1 fully landed
// before the tile-end barrier releases readers.
// T2 swizzle: linear LDS dest; source chunk pre-XORed with row&7; ds_read
// applies the same XOR (involution).
// ---------------------------------------------------------------------------
__global__ __launch_bounds__(512, 2) void gemm1_qk_exp(
    const unsigned short* __restrict__ A,   // qT [b][2048][512]
    const unsigned short* __restrict__ B,   // kT [b][2048][512]
    unsigned short* __restrict__ E,         // [b][2048][2048]
    float* __restrict__ rpart,              // [16][BS][2048]
    float scale)
{
    constexpr int K = SEQ;      // 512
    constexpr int N = DKDIM;    // 2048
    constexpr int NT = K / 64;  // 8 K-tiles

    int b = blockIdx.z;
    const unsigned short* Ab = A + ((size_t)b * DKDIM + blockIdx.y * 256) * K;
    const unsigned short* Bb = B + ((size_t)b * DKDIM + blockIdx.x * 256) * K;

    __shared__ unsigned short lds[2][2][256 * 64];   // [buf][A/B][row*64 + chunk*8]

    int t = threadIdx.x;            // 0..511
    int w = t >> 6, l = t & 63;
    int wm = w >> 2, wn = w & 3;    // 2M x 4N waves
    int lm = l & 15, lg = l >> 4;

    int srow = t >> 3;                       // 0..63
    int schunk = (t & 7) ^ (srow & 7);       // pre-swizzled source chunk

    // A-half h: rows h*64+srow and h*64+128+srow; dest h*4096 + t*8 (lane-linear)
    auto stageA = [&](int buf, int h, int tt) {
        const unsigned short* g0 = Ab + (size_t)(h * 64 + srow) * K + tt * 64 + schunk * 8;
        unsigned short* d = &lds[buf][0][h * 4096 + t * 8];
        gload_lds16(g0, d);
        gload_lds16(g0 + (size_t)128 * K, d + 8192);
    };
    // B-half h: rows h*32 + (t>>8)*64 + (srow&31), and +128; dest row*64+(t&7)*8
    auto stageB = [&](int buf, int h, int tt) {
        int row = h * 32 + ((t >> 8) << 6) + (srow & 31);
        const unsigned short* g0 = Bb + (size_t)row * K + tt * 64 + schunk * 8;
        unsigned short* d = &lds[buf][1][row * 64 + (t & 7) * 8];
        gload_lds16(g0, d);
        gload_lds16(g0 + (size_t)128 * K, d + 8192);
    };
    auto rdA = [&](int buf, int ar, int kc) {
        return *reinterpret_cast<const bf16x8*>(&lds[buf][0][ar * 64 + ((kc ^ (ar & 7)) << 3)]);
    };
    auto rdB = [&](int buf, int br, int kc) {
        return *reinterpret_cast<const bf16x8*>(&lds[buf][1][br * 64 + ((kc ^ (br & 7)) << 3)]);
    };

    f32x4 acc[8][4] = {};
    bf16x8 a0[2][4], a1[2][4], b0[2][2], b1[2][2];

    // prologue: tile0 complete (8 loads), tile1 {A0,B0,B1} (6 loads)
    stageA(0, 0, 0); stageB(0, 0, 0); stageB(0, 1, 0); stageA(0, 1, 0);
    stageA(1, 0, 1); stageB(1, 0, 1); stageB(1, 1, 1);
    asm volatile("s_waitcnt vmcnt(6)" ::: "memory");
    PH_BARRIER();

#define MFMA_Q(AF, BF, MO, NO)                                                  \
    _Pragma("unroll") for (int ks = 0; ks < 2; ++ks)                            \
    _Pragma("unroll") for (int mf = 0; mf < 4; ++mf)                            \
    _Pragma("unroll") for (int nf = 0; nf < 2; ++nf)                            \
        acc[(MO) + mf][(NO) + nf] = __builtin_amdgcn_mfma_f32_16x16x32_bf16(    \
            BF[ks][nf], AF[ks][mf], acc[(MO) + mf][(NO) + nf], 0, 0, 0);

    #pragma unroll 2
    for (int tt = 0; tt < NT; ++tt) {
        int buf = tt & 1;
        // ---- phase 0: q00 ----
        #pragma unroll
        for (int ks = 0; ks < 2; ++ks) {
            #pragma unroll
            for (int mf = 0; mf < 4; ++mf)
                a0[ks][mf] = rdA(buf, wm * 128 + mf * 16 + lm, ks * 4 + lg);
            #pragma unroll
            for (int nf = 0; nf < 2; ++nf)
                b0[ks][nf] = rdB(buf, wn * 64 + nf * 16 + lm, ks * 4 + lg);
        }
        if (tt + 1 < NT) stageA(buf ^ 1, 1, tt + 1);
        PH_BARRIER();
        asm volatile("s_waitcnt lgkmcnt(0)" ::: "memory");
        __builtin_amdgcn_sched_barrier(0);
        __builtin_amdgcn_s_setprio(1);
        MFMA_Q(a0, b0, 0, 0)
        __builtin_amdgcn_s_setprio(0);
        PH_BARRIER();
        // ---- phase 1: q01 ----
        #pragma unroll
        for (int ks = 0; ks < 2; ++ks)
            #pragma unroll
            for (int nf = 0; nf < 2; ++nf)
                b1[ks][nf] = rdB(buf, wn * 64 + (nf + 2) * 16 + lm, ks * 4 + lg);
        if (tt + 2 < NT) stageA(buf, 0, tt + 2);
        PH_BARRIER();
        asm volatile("s_waitcnt lgkmcnt(0)" ::: "memory");
        __builtin_amdgcn_sched_barrier(0);
        __builtin_amdgcn_s_setprio(1);
        MFMA_Q(a0, b1, 0, 2)
        __builtin_amdgcn_s_setprio(0);
        PH_BARRIER();
        // ---- phase 2: q11 ----
        #pragma unroll
        for (int ks = 0; ks < 2; ++ks)
            #pragma unroll
            for (int mf = 0; mf < 4; ++mf)
                a1[ks][mf] = rdA(buf, wm * 128 + 64 + mf * 16 + lm, ks * 4 + lg);
        if (tt + 2 < NT) stageB(buf, 0, tt + 2);
        PH_BARRIER();
        asm volatile("s_waitcnt lgkmcnt(0)" ::: "memory");
        __builtin_amdgcn_sched_barrier(0);
        __builtin_amdgcn_s_setprio(1);
        MFMA_Q(a1, b1, 4, 2)
        __builtin_amdgcn_s_setprio(0);
        PH_BARRIER();
        // ---- phase 3: q10 (a1,b0 held in regs) ----
        if (tt + 2 < NT) stageB(buf, 1, tt + 2);
        PH_BARRIER();
        __builtin_amdgcn_s_setprio(1);
        MFMA_Q(a1, b0, 4, 0)
        __builtin_amdgcn_s_setprio(0);
        if (tt < NT - 2) {
            asm volatile("s_waitcnt vmcnt(6)" ::: "memory");
        } else if (tt == NT - 2) {
            asm volatile("s_waitcnt vmcnt(0)" ::: "memory");
        }
        PH_BARRIER();
    }
#undef MFMA_Q

    // ---- epilogue: exp, bf16 store (n-consecutive), fused column sums ----
    unsigned short* Eb = E + (size_t)b * DKDIM * DKDIM;
    int nbase = blockIdx.x * 256 + wn * 64 + lg * 4;
    float csum[16];
    #pragma unroll
    for (int x = 0; x < 16; ++x) csum[x] = 0.f;
    #pragma unroll
    for (int mfg = 0; mfg < 8; ++mfg) {
        int row = blockIdx.y * 256 + wm * 128 + (mfg >> 2) * 64 + (mfg & 3) * 16 + lm;
        #pragma unroll
        for (int nf = 0; nf < 4; ++nf) {
            f32x4 a = acc[mfg][nf];
            float e0 = __expf(scale * a[0]);
            float e1 = __expf(scale * a[1]);
            float e2 = __expf(scale * a[2]);
            float e3 = __expf(scale * a[3]);
            csum[nf * 4 + 0] += e0;
            csum[nf * 4 + 1] += e1;
            csum[nf * 4 + 2] += e2;
            csum[nf * 4 + 3] += e3;
            ushort4 o;
            o.x = f2bf(e0); o.y = f2bf(e1); o.z = f2bf(e2); o.w = f2bf(e3);
            *reinterpret_cast<ushort4*>(&Eb[(size_t)row * N + nbase + nf * 16]) = o;
        }
    }
    #pragma unroll
    for (int x = 0; x < 16; ++x) {
        float s = csum[x];
        s += __shfl_xor(s, 1, 64);
        s += __shfl_xor(s, 2, 64);
        s += __shfl_xor(s, 4, 64);
        s += __shfl_xor(s, 8, 64);
        csum[x] = s;
    }
    float val = 0.f;
    #pragma unroll
    for (int x = 0; x < 16; ++x)
        if (lm == x) val = csum[x];
    int e = blockIdx.x * 256 + wn * 64 + (lm >> 2) * 16 + lg * 4 + (lm & 3);
    rpart[((size_t)(blockIdx.y * 2 + wm) * BS + b) * (size_t)DKDIM + e] = val;
}

// ---------------------------------------------------------------------------
// GEMM2: out = v' * E^T : A=vp [512][2048], B=E [2048][2048], f32 out.
// 128x128 tile m97-style (verified in round 2).
// ---------------------------------------------------------------------------
__global__ __launch_bounds__(256) void gemm2_av_kernel(
    const unsigned short* __restrict__ A,
    const unsigned short* __restrict__ B,
    float* __restrict__ C,
    int M, int N, int K,
    long Abs, long Bbs, long Cbs)
{
    int b = blockIdx.z;
    A += (size_t)b * Abs;
    B += (size_t)b * Bbs;
    int m0 = blockIdx.y * 128;
    int n0 = blockIdx.x * 128;

    __shared__ unsigned short lA[128 * 64];
    __shared__ unsigned short lB[128 * 64];

    int t = threadIdx.x;
    int w = t >> 6, l = t & 63;
    int wm = w >> 1, wn = w & 1;

    f32x4 acc[4][4] = {};

    int srow = (l >> 3);
    int scol = (l & 7) * 8;

    for (int k0 = 0; k0 < K; k0 += 64) {
        #pragma unroll
        for (int rnd = 0; rnd < 4; ++rnd) {
            int row = rnd * 32 + w * 8 + srow;
            gload_lds16(A + (size_t)(m0 + row) * K + k0 + scol, &lA[row * 64 + scol]);
            gload_lds16(B + (size_t)(n0 + row) * K + k0 + scol, &lB[row * 64 + scol]);
        }
        __syncthreads();
        #pragma unroll
        for (int ks = 0; ks < 2; ++ks) {
            bf16x8 af[4], bfr[4];
            #pragma unroll
            for (int f = 0; f < 4; ++f) {
                int arow = wm * 64 + f * 16 + (l & 15);
                int koff = ks * 32 + (l >> 4) * 8;
                af[f]  = *reinterpret_cast<const bf16x8*>(&lA[arow * 64 + koff]);
                int brow = wn * 64 + f * 16 + (l & 15);
                bfr[f] = *reinterpret_cast<const bf16x8*>(&lB[brow * 64 + koff]);
            }
            #pragma unroll
            for (int i = 0; i < 4; ++i)
                #pragma unroll
                for (int j = 0; j < 4; ++j)
                    acc[i][j] = __builtin_amdgcn_mfma_f32_16x16x32_bf16(bfr[j], af[i], acc[i][j], 0, 0, 0);
        }
        __syncthreads();
    }

    float* Cf = C + (size_t)b * Cbs;
    int mbase = m0 + wm * 64 + (l & 15);
    int nbase = n0 + wn * 64 + (l >> 4) * 4;
    #pragma unroll
    for (int i = 0; i < 4; ++i)
        #pragma unroll
        for (int j = 0; j < 4; ++j)
            *reinterpret_cast<f32x4*>(&Cf[(size_t)(mbase + i * 16) * N + nbase + j * 16]) = acc[i][j];
}

// ---------------------------------------------------------------------------
// rinv[b][e] = 1 / sum over 16 partials
// ---------------------------------------------------------------------------
__global__ __launch_bounds__(256) void colsum_finish(
    const float* __restrict__ rpart, float* __restrict__ rinv)
{
    int i = blockIdx.x * 256 + threadIdx.x;
    float s = 0.f;
    #pragma unroll
    for (int p = 0; p < 16; ++p) s += rpart[(size_t)p * BS * DKDIM + i];
    rinv[i] = 1.0f / s;
}

// ---------------------------------------------------------------------------
// v'[b][s][e] = bf16( v[b][s][e] * rinv[b][e] )
// ---------------------------------------------------------------------------
__global__ __launch_bounds__(256) void vprime_kernel(
    const float* __restrict__ v, const float* __restrict__ rinv,
    unsigned short* __restrict__ vp)
{
    size_t i4 = ((size_t)blockIdx.x * 256 + threadIdx.x) * 4;
    int e = (int)(i4 & (DKDIM - 1));
    int b = (int)(i4 >> 20);
    float4 v4 = *reinterpret_cast<const float4*>(&v[i4]);
    float4 r4 = *reinterpret_cast<const float4*>(&rinv[(size_t)b * DKDIM + e]);
    ushort4 o;
    o.x = f2bf(v4.x * r4.x);
    o.y = f2bf(v4.y * r4.y);
    o.z = f2bf(v4.z * r4.z);
    o.w = f2bf(v4.w * r4.w);
    *reinterpret_cast<ushort4*>(&vp[i4]) = o;
}

extern "C" void kernel_launch(void* const* d_in, const int* in_sizes, int n_in,
                              void* d_out, int out_size, void* d_ws, size_t ws_size,
                              hipStream_t stream) {
    const float* q = (const float*)d_in[0];
    const float* k = (const float*)d_in[1];
    const float* v = (const float*)d_in[2];
    float* out = (float*)d_out;

    char* ws = (char*)d_ws;
    unsigned short* qT = (unsigned short*)(ws);                        // 16 MB
    unsigned short* kT = (unsigned short*)(ws + 16777216);             // 16 MB
    unsigned short* E  = (unsigned short*)(ws + 33554432);             // 64 MB
    float* rpart       = (float*)(ws + 100663296);                     // 1 MB (16x8x2048 f32)
    float* rinv        = (float*)(ws + 102760448);                     // 64 KB
    unsigned short* vp = (unsigned short*)(ws + 103809024);            // 16 MB

    const float scale = 0.022097086912079608f;  // 1/sqrt(2048)

    transpose_conv_kernel<<<dim3(DKDIM / 64, SEQ / 64, 2 * BS), 256, 0, stream>>>(q, k, qT, kT);

    gemm1_qk_exp<<<dim3(DKDIM / 256, DKDIM / 256, BS), 512, 0, stream>>>(
        qT, kT, E, rpart, scale);

    colsum_finish<<<dim3(BS * DKDIM / 256), 256, 0, stream>>>(rpart, rinv);

    vprime_kernel<<<dim3(BS * SEQ * DKDIM / 1024), 256, 0, stream>>>(v, rinv, vp);

    gemm2_av_kernel<<<dim3(DKDIM / 128, SEQ / 128, BS), 256, 0, stream>>>(
        vp, E, out, SEQ, DKDIM, DKDIM,
        (long)SEQ * DKDIM, (long)DKDIM * DKDIM, (long)SEQ * DKDIM);
}

// Round 5
// 123.550 us; speedup vs baseline: 1.1999x; 1.0934x over previous
//
#include <hip/hip_runtime.h>
#include <hip/hip_bf16.h>

#define BS 8
#define SEQ 512
#define DKDIM 2048

using bf16x8 = __attribute__((ext_vector_type(8))) __bf16;
using f32x4  = __attribute__((ext_vector_type(4))) float;

__device__ __forceinline__ unsigned short f2bf(float f) {
    unsigned int u = __builtin_bit_cast(unsigned int, f);
    u += 0x7FFFu + ((u >> 16) & 1u);
    return (unsigned short)(u >> 16);
}

__device__ __forceinline__ void gload_lds16(const unsigned short* g, unsigned short* l) {
    __builtin_amdgcn_global_load_lds(
        (const __attribute__((address_space(1))) unsigned int*)g,
        (__attribute__((address_space(3))) unsigned int*)l, 16, 0, 0);
}

#define PH_BARRIER() asm volatile("s_barrier" ::: "memory")

// ---------------------------------------------------------------------------
// Transpose+convert: in [SEQ][DK] f32 (per batch) -> out [DK][SEQ] bf16
// ---------------------------------------------------------------------------
__global__ __launch_bounds__(256) void transpose_conv_kernel(
    const float* __restrict__ q, const float* __restrict__ k,
    unsigned short* __restrict__ qT, unsigned short* __restrict__ kT)
{
    int z = blockIdx.z;
    const float* in = (z < BS) ? q : k;
    unsigned short* out = (z < BS) ? qT : kT;
    int b = z & (BS - 1);
    in  += (size_t)b * SEQ * DKDIM;
    out += (size_t)b * DKDIM * SEQ;
    int s0 = blockIdx.y * 64;
    int d0 = blockIdx.x * 64;
    __shared__ unsigned short tile[64][66];
    int t = threadIdx.x;
    int tr  = t >> 4;
    int tc4 = (t & 15) * 4;
    #pragma unroll
    for (int p = 0; p < 4; ++p) {
        int s = p * 16 + tr;
        float4 v4 = *reinterpret_cast<const float4*>(&in[(size_t)(s0 + s) * DKDIM + d0 + tc4]);
        tile[s][tc4 + 0] = f2bf(v4.x);
        tile[s][tc4 + 1] = f2bf(v4.y);
        tile[s][tc4 + 2] = f2bf(v4.z);
        tile[s][tc4 + 3] = f2bf(v4.w);
    }
    __syncthreads();
    #pragma unroll
    for (int p = 0; p < 4; ++p) {
        int d = p * 16 + tr;
        ushort4 o;
        o.x = tile[tc4 + 0][d];
        o.y = tile[tc4 + 1][d];
        o.z = tile[tc4 + 2][d];
        o.w = tile[tc4 + 3][d];
        *reinterpret_cast<ushort4*>(&out[(size_t)(d0 + d) * SEQ + s0 + tc4]) = o;
    }
}

// ---------------------------------------------------------------------------
// GEMM1: E = exp(scale*(qT kT^T)), bf16, + fused column partial sums.
// 256x256, BK=64, 8 waves (2Mx4N), 4 phases/K-tile — schedule verified r4.
// This round: all ds_read offsets hoisted to registers (aoff/boff), stage
// uses 4 precomputed rolling global pointers. Schedule IDENTICAL to r4.
// ---------------------------------------------------------------------------
__global__ __launch_bounds__(512, 2) void gemm1_qk_exp(
    const unsigned short* __restrict__ A,   // qT [b][2048][512]
    const unsigned short* __restrict__ B,   // kT [b][2048][512]
    unsigned short* __restrict__ E,         // [b][2048][2048]
    float* __restrict__ rpart,              // [16][BS][2048]
    float scale)
{
    constexpr int K = SEQ;      // 512
    constexpr int N = DKDIM;    // 2048
    constexpr int NT = K / 64;  // 8

    int b = blockIdx.z;
    const unsigned short* Ab = A + ((size_t)b * DKDIM + blockIdx.y * 256) * K;
    const unsigned short* Bb = B + ((size_t)b * DKDIM + blockIdx.x * 256) * K;

    __shared__ unsigned short lds[2][2][256 * 64];

    int t = threadIdx.x;
    int w = t >> 6, l = t & 63;
    int wm = w >> 2, wn = w & 3;
    int lm = l & 15, lg = l >> 4;

    int srow = t >> 3;
    int schunk = (t & 7) ^ (srow & 7);

    // hoisted global stage pointers (advance by tt*64 per call)
    const unsigned short* pA0 = Ab + (size_t)srow * K + schunk * 8;
    const unsigned short* pA1 = Ab + (size_t)(64 + srow) * K + schunk * 8;
    int browB = ((t >> 8) << 6) + (srow & 31);
    const unsigned short* pB0 = Bb + (size_t)browB * K + schunk * 8;
    const unsigned short* pB1 = Bb + (size_t)(32 + browB) * K + schunk * 8;
    unsigned short* dA = (unsigned short*)0;  // dests are static per (buf,side)

    // hoisted ds_read byte offsets
    int aoff[2][4][2], boff[4][2];
    #pragma unroll
    for (int h = 0; h < 2; ++h)
        #pragma unroll
        for (int mf = 0; mf < 4; ++mf)
            #pragma unroll
            for (int ks = 0; ks < 2; ++ks) {
                int arow = wm * 128 + h * 64 + mf * 16 + lm;
                int kc = ks * 4 + lg;
                aoff[h][mf][ks] = (arow * 64 + ((kc ^ (arow & 7)) << 3)) * 2;
            }
    #pragma unroll
    for (int nf = 0; nf < 4; ++nf)
        #pragma unroll
        for (int ks = 0; ks < 2; ++ks) {
            int brow = wn * 64 + nf * 16 + lm;
            int kc = ks * 4 + lg;
            boff[nf][ks] = (brow * 64 + ((kc ^ (brow & 7)) << 3)) * 2;
        }

#define LD_A(buf, h, mf, ks) \
    (*reinterpret_cast<const bf16x8*>((const char*)(&lds[buf][0][0]) + aoff[h][mf][ks]))
#define LD_B(buf, nf, ks) \
    (*reinterpret_cast<const bf16x8*>((const char*)(&lds[buf][1][0]) + boff[nf][ks]))
#define STAGE_A(buf, h, tt) do {                                               \
        const unsigned short* g = ((h) ? pA1 : pA0) + (tt) * 64;               \
        unsigned short* d = &lds[buf][0][(h) * 4096 + t * 8];                  \
        gload_lds16(g, d);                                                     \
        gload_lds16(g + (size_t)128 * K, d + 8192);                            \
    } while (0)
#define STAGE_B(buf, h, tt) do {                                               \
        const unsigned short* g = ((h) ? pB1 : pB0) + (tt) * 64;               \
        unsigned short* d = &lds[buf][1][(h) * 2048 + ((t >> 8) << 12) + ((t & 255) * 8)]; \
        gload_lds16(g, d);                                                     \
        gload_lds16(g + (size_t)128 * K, d + 8192);                            \
    } while (0)

    f32x4 acc[8][4] = {};
    bf16x8 a0[2][4], a1[2][4], b0[2][2], b1[2][2];

    STAGE_A(0, 0, 0); STAGE_B(0, 0, 0); STAGE_B(0, 1, 0); STAGE_A(0, 1, 0);
    STAGE_A(1, 0, 1); STAGE_B(1, 0, 1); STAGE_B(1, 1, 1);
    asm volatile("s_waitcnt vmcnt(6)" ::: "memory");
    PH_BARRIER();

#define MFMA_Q(AF, BF, MO, NO)                                                  \
    _Pragma("unroll") for (int ks = 0; ks < 2; ++ks)                            \
    _Pragma("unroll") for (int mf = 0; mf < 4; ++mf)                            \
    _Pragma("unroll") for (int nf = 0; nf < 2; ++nf)                            \
        acc[(MO) + mf][(NO) + nf] = __builtin_amdgcn_mfma_f32_16x16x32_bf16(    \
            BF[ks][nf], AF[ks][mf], acc[(MO) + mf][(NO) + nf], 0, 0, 0);

    #pragma unroll 2
    for (int tt = 0; tt < NT; ++tt) {
        int buf = tt & 1;
        // ---- phase 0: q00 ----
        #pragma unroll
        for (int ks = 0; ks < 2; ++ks) {
            #pragma unroll
            for (int mf = 0; mf < 4; ++mf) a0[ks][mf] = LD_A(buf, 0, mf, ks);
            #pragma unroll
            for (int nf = 0; nf < 2; ++nf) b0[ks][nf] = LD_B(buf, nf, ks);
        }
        if (tt + 1 < NT) STAGE_A(buf ^ 1, 1, tt + 1);
        PH_BARRIER();
        asm volatile("s_waitcnt lgkmcnt(0)" ::: "memory");
        __builtin_amdgcn_sched_barrier(0);
        __builtin_amdgcn_s_setprio(1);
        MFMA_Q(a0, b0, 0, 0)
        __builtin_amdgcn_s_setprio(0);
        PH_BARRIER();
        // ---- phase 1: q01 ----
        #pragma unroll
        for (int ks = 0; ks < 2; ++ks)
            #pragma unroll
            for (int nf = 0; nf < 2; ++nf) b1[ks][nf] = LD_B(buf, nf + 2, ks);
        if (tt + 2 < NT) STAGE_A(buf, 0, tt + 2);
        PH_BARRIER();
        asm volatile("s_waitcnt lgkmcnt(0)" ::: "memory");
        __builtin_amdgcn_sched_barrier(0);
        __builtin_amdgcn_s_setprio(1);
        MFMA_Q(a0, b1, 0, 2)
        __builtin_amdgcn_s_setprio(0);
        PH_BARRIER();
        // ---- phase 2: q11 ----
        #pragma unroll
        for (int ks = 0; ks < 2; ++ks)
            #pragma unroll
            for (int mf = 0; mf < 4; ++mf) a1[ks][mf] = LD_A(buf, 1, mf, ks);
        if (tt + 2 < NT) STAGE_B(buf, 0, tt + 2);
        PH_BARRIER();
        asm volatile("s_waitcnt lgkmcnt(0)" ::: "memory");
        __builtin_amdgcn_sched_barrier(0);
        __builtin_amdgcn_s_setprio(1);
        MFMA_Q(a1, b1, 4, 2)
        __builtin_amdgcn_s_setprio(0);
        PH_BARRIER();
        // ---- phase 3: q10 ----
        if (tt + 2 < NT) STAGE_B(buf, 1, tt + 2);
        PH_BARRIER();
        __builtin_amdgcn_s_setprio(1);
        MFMA_Q(a1, b0, 4, 0)
        __builtin_amdgcn_s_setprio(0);
        if (tt < NT - 2) {
            asm volatile("s_waitcnt vmcnt(6)" ::: "memory");
        } else if (tt == NT - 2) {
            asm volatile("s_waitcnt vmcnt(0)" ::: "memory");
        }
        PH_BARRIER();
    }
#undef MFMA_Q
#undef LD_A
#undef LD_B
#undef STAGE_A
#undef STAGE_B

    // ---- epilogue: exp, bf16 store, fused column sums ----
    unsigned short* Eb = E + (size_t)b * DKDIM * DKDIM;
    int nbase = blockIdx.x * 256 + wn * 64 + lg * 4;
    float csum[16];
    #pragma unroll
    for (int x = 0; x < 16; ++x) csum[x] = 0.f;
    #pragma unroll
    for (int mfg = 0; mfg < 8; ++mfg) {
        int row = blockIdx.y * 256 + wm * 128 + (mfg >> 2) * 64 + (mfg & 3) * 16 + lm;
        #pragma unroll
        for (int nf = 0; nf < 4; ++nf) {
            f32x4 a = acc[mfg][nf];
            float e0 = __expf(scale * a[0]);
            float e1 = __expf(scale * a[1]);
            float e2 = __expf(scale * a[2]);
            float e3 = __expf(scale * a[3]);
            csum[nf * 4 + 0] += e0;
            csum[nf * 4 + 1] += e1;
            csum[nf * 4 + 2] += e2;
            csum[nf * 4 + 3] += e3;
            ushort4 o;
            o.x = f2bf(e0); o.y = f2bf(e1); o.z = f2bf(e2); o.w = f2bf(e3);
            *reinterpret_cast<ushort4*>(&Eb[(size_t)row * N + nbase + nf * 16]) = o;
        }
    }
    #pragma unroll
    for (int x = 0; x < 16; ++x) {
        float s = csum[x];
        s += __shfl_xor(s, 1, 64);
        s += __shfl_xor(s, 2, 64);
        s += __shfl_xor(s, 4, 64);
        s += __shfl_xor(s, 8, 64);
        csum[x] = s;
    }
    float val = 0.f;
    #pragma unroll
    for (int x = 0; x < 16; ++x)
        if (lm == x) val = csum[x];
    int e = blockIdx.x * 256 + wn * 64 + (lm >> 2) * 16 + lg * 4 + (lm & 3);
    rpart[((size_t)(blockIdx.y * 2 + wm) * BS + b) * (size_t)DKDIM + e] = val;
}

// ---------------------------------------------------------------------------
// GEMM2: out = vp * E^T. BM=256 x BN=128, BK=64, NT=32, 8 waves (4Mx2N),
// wave tile 64x64, 4 quadrant phases of 8 MFMA, counted vmcnt(5).
// Read-group-matched halves: A split by row&32 (a-lo=mf01 read ph0,
// a-hi=mf23 read ph2); B split by row&32 (b-lo=nf01 ph0, b-hi=nf23 ph1).
// Stage slots: ph0 Bh(t+1)->buf^1 | ph1 Alo(t+2)->buf | ph2 Bl(t+2)->buf
// | ph3 Ahi(t+2)->buf.  Each target's last reader phase strictly precedes
// its staging phase (lgkmcnt(0)+barrier between).  Tile-end vmcnt(5)
// leaves exactly t+2's {Alo2,Bl1,Ahi2} outstanding => t+1 fully landed.
// Prologue: t0 all (6 loads), t1 {Alo,Bl,Ahi} (5), vmcnt(5).
// LDS: [2][A 256*64 | B 128*64] = 96 KB.
// ---------------------------------------------------------------------------
__global__ __launch_bounds__(512, 2) void gemm2_av_pipe(
    const unsigned short* __restrict__ A,   // vp [b][512][2048]
    const unsigned short* __restrict__ B,   // E  [b][2048][2048]
    float* __restrict__ C)                  // out [b][512][2048]
{
    constexpr int K = DKDIM;    // 2048
    constexpr int N = DKDIM;
    constexpr int NT = K / 64;  // 32

    int b = blockIdx.z;
    const unsigned short* Ab = A + ((size_t)b * SEQ + blockIdx.y * 256) * K;
    const unsigned short* Bb = B + ((size_t)b * DKDIM + blockIdx.x * 128) * K;

    __shared__ unsigned short lds[2][256 * 64 + 128 * 64];   // A then B

    int t = threadIdx.x;
    int w = t >> 6, l = t & 63;
    int wm = w >> 1, wn = w & 1;     // 4M x 2N
    int lm = l & 15, lg = l >> 4;

    int srow = t >> 3;
    int schunk = (t & 7) ^ (srow & 7);

    int rA = (srow & 31) + ((t >> 8) << 6);          // + hi*32; rows r, r+128
    const unsigned short* pA = Ab + (size_t)rA * K + schunk * 8;
    const unsigned short* pB = Bb + (size_t)rA * K + schunk * 8;   // B rows 0..127 same pattern

    int aoff[4][2], boff[4][2];
    #pragma unroll
    for (int mf = 0; mf < 4; ++mf)
        #pragma unroll
        for (int ks = 0; ks < 2; ++ks) {
            int arow = wm * 64 + mf * 16 + lm;
            int kc = ks * 4 + lg;
            aoff[mf][ks] = (arow * 64 + ((kc ^ (arow & 7)) << 3)) * 2;
            int brow = wn * 64 + mf * 16 + lm;
            boff[mf][ks] = (16384 + brow * 64 + ((kc ^ (brow & 7)) << 3)) * 2;
        }

#define LD_A2(buf, mf, ks) \
    (*reinterpret_cast<const bf16x8*>((const char*)(&lds[buf][0]) + aoff[mf][ks]))
#define LD_B2(buf, nf, ks) \
    (*reinterpret_cast<const bf16x8*>((const char*)(&lds[buf][0]) + boff[nf][ks]))
#define STAGE_A2(buf, hi, tt) do {                                             \
        const unsigned short* g = pA + (hi) * 32 * K + (tt) * 64;              \
        unsigned short* d = &lds[buf][(hi) * 2048 + ((t >> 8) << 12) + (t & 255) * 8]; \
        gload_lds16(g, d);                                                     \
        gload_lds16(g + (size_t)128 * K, d + 8192);                            \
    } while (0)
#define STAGE_B2(buf, hi, tt) do {                                             \
        const unsigned short* g = pB + (hi) * 32 * K + (tt) * 64;              \
        unsigned short* d = &lds[buf][16384 + (hi) * 2048 + ((t >> 8) << 12) + (t & 255) * 8]; \
        gload_lds16(g, d);                                                     \
    } while (0)

    f32x4 acc[4][4] = {};
    bf16x8 alo[2][2], ahi[2][2], blo[2][2], bhi[2][2];

    STAGE_A2(0, 0, 0); STAGE_A2(0, 1, 0); STAGE_B2(0, 0, 0); STAGE_B2(0, 1, 0);
    STAGE_A2(1, 0, 1); STAGE_B2(1, 0, 1); STAGE_A2(1, 1, 1);
    asm volatile("s_waitcnt vmcnt(5)" ::: "memory");
    PH_BARRIER();

#define MFMA_Q2(AF, BF, MO, NO)                                                 \
    _Pragma("unroll") for (int ks = 0; ks < 2; ++ks)                            \
    _Pragma("unroll") for (int mf = 0; mf < 2; ++mf)                            \
    _Pragma("unroll") for (int nf = 0; nf < 2; ++nf)                            \
        acc[(MO) + mf][(NO) + nf] = __builtin_amdgcn_mfma_f32_16x16x32_bf16(    \
            BF[ks][nf], AF[ks][mf], acc[(MO) + mf][(NO) + nf], 0, 0, 0);

    #pragma unroll 2
    for (int tt = 0; tt < NT; ++tt) {
        int buf = tt & 1;
        // ---- ph0: alo x blo ----
        #pragma unroll
        for (int ks = 0; ks < 2; ++ks)
            #pragma unroll
            for (int f = 0; f < 2; ++f) {
                alo[ks][f] = LD_A2(buf, f, ks);
                blo[ks][f] = LD_B2(buf, f, ks);
            }
        if (tt + 1 < NT) STAGE_B2(buf ^ 1, 1, tt + 1);
        PH_BARRIER();
        asm volatile("s_waitcnt lgkmcnt(0)" ::: "memory");
        __builtin_amdgcn_sched_barrier(0);
        __builtin_amdgcn_s_setprio(1);
        MFMA_Q2(alo, blo, 0, 0)
        __builtin_amdgcn_s_setprio(0);
        PH_BARRIER();
        // ---- ph1: alo x bhi ----
        #pragma unroll
        for (int ks = 0; ks < 2; ++ks)
            #pragma unroll
            for (int f = 0; f < 2; ++f) bhi[ks][f] = LD_B2(buf, f + 2, ks);
        if (tt + 2 < NT) STAGE_A2(buf, 0, tt + 2);
        PH_BARRIER();
        asm volatile("s_waitcnt lgkmcnt(0)" ::: "memory");
        __builtin_amdgcn_sched_barrier(0);
        __builtin_amdgcn_s_setprio(1);
        MFMA_Q2(alo, bhi, 0, 2)
        __builtin_amdgcn_s_setprio(0);
        PH_BARRIER();
        // ---- ph2: ahi x bhi ----
        #pragma unroll
        for (int ks = 0; ks < 2; ++ks)
            #pragma unroll
            for (int f = 0; f < 2; ++f) ahi[ks][f] = LD_A2(buf, f + 2, ks);
        if (tt + 2 < NT) STAGE_B2(buf, 0, tt + 2);
        PH_BARRIER();
        asm volatile("s_waitcnt lgkmcnt(0)" ::: "memory");
        __builtin_amdgcn_sched_barrier(0);
        __builtin_amdgcn_s_setprio(1);
        MFMA_Q2(ahi, bhi, 2, 2)
        __builtin_amdgcn_s_setprio(0);
        PH_BARRIER();
        // ---- ph3: ahi x blo (regs held) ----
        if (tt + 2 < NT) STAGE_A2(buf, 1, tt + 2);
        PH_BARRIER();
        __builtin_amdgcn_s_setprio(1);
        MFMA_Q2(ahi, blo, 2, 0)
        __builtin_amdgcn_s_setprio(0);
        if (tt < NT - 2) {
            asm volatile("s_waitcnt vmcnt(5)" ::: "memory");
        } else if (tt == NT - 2) {
            asm volatile("s_waitcnt vmcnt(0)" ::: "memory");
        }
        PH_BARRIER();
    }
#undef MFMA_Q2
#undef LD_A2
#undef LD_B2
#undef STAGE_A2
#undef STAGE_B2

    float* Cf = C + (size_t)b * SEQ * DKDIM;
    int mbase = blockIdx.y * 256 + wm * 64 + lm;
    int nbase = blockIdx.x * 128 + wn * 64 + lg * 4;
    #pragma unroll
    for (int i = 0; i < 4; ++i)
        #pragma unroll
        for (int j = 0; j < 4; ++j)
            *reinterpret_cast<f32x4*>(&Cf[(size_t)(mbase + i * 16) * N + nbase + j * 16]) = acc[i][j];
}

// ---------------------------------------------------------------------------
// rinv[b][e] = 1 / sum over 16 partials
// ---------------------------------------------------------------------------
__global__ __launch_bounds__(256) void colsum_finish(
    const float* __restrict__ rpart, float* __restrict__ rinv)
{
    int i = blockIdx.x * 256 + threadIdx.x;
    float s = 0.f;
    #pragma unroll
    for (int p = 0; p < 16; ++p) s += rpart[(size_t)p * BS * DKDIM + i];
    rinv[i] = 1.0f / s;
}

// ---------------------------------------------------------------------------
// v'[b][s][e] = bf16( v[b][s][e] * rinv[b][e] )
// ---------------------------------------------------------------------------
__global__ __launch_bounds__(256) void vprime_kernel(
    const float* __restrict__ v, const float* __restrict__ rinv,
    unsigned short* __restrict__ vp)
{
    size_t i4 = ((size_t)blockIdx.x * 256 + threadIdx.x) * 4;
    int e = (int)(i4 & (DKDIM - 1));
    int b = (int)(i4 >> 20);
    float4 v4 = *reinterpret_cast<const float4*>(&v[i4]);
    float4 r4 = *reinterpret_cast<const float4*>(&rinv[(size_t)b * DKDIM + e]);
    ushort4 o;
    o.x = f2bf(v4.x * r4.x);
    o.y = f2bf(v4.y * r4.y);
    o.z = f2bf(v4.z * r4.z);
    o.w = f2bf(v4.w * r4.w);
    *reinterpret_cast<ushort4*>(&vp[i4]) = o;
}

extern "C" void kernel_launch(void* const* d_in, const int* in_sizes, int n_in,
                              void* d_out, int out_size, void* d_ws, size_t ws_size,
                              hipStream_t stream) {
    const float* q = (const float*)d_in[0];
    const float* k = (const float*)d_in[1];
    const float* v = (const float*)d_in[2];
    float* out = (float*)d_out;

    char* ws = (char*)d_ws;
    unsigned short* qT = (unsigned short*)(ws);                        // 16 MB
    unsigned short* kT = (unsigned short*)(ws + 16777216);             // 16 MB
    unsigned short* E  = (unsigned short*)(ws + 33554432);             // 64 MB
    float* rpart       = (float*)(ws + 100663296);                     // 1 MB
    float* rinv        = (float*)(ws + 102760448);                     // 64 KB
    unsigned short* vp = (unsigned short*)(ws + 103809024);            // 16 MB

    const float scale = 0.022097086912079608f;  // 1/sqrt(2048)

    transpose_conv_kernel<<<dim3(DKDIM / 64, SEQ / 64, 2 * BS), 256, 0, stream>>>(q, k, qT, kT);

    gemm1_qk_exp<<<dim3(DKDIM / 256, DKDIM / 256, BS), 512, 0, stream>>>(
        qT, kT, E, rpart, scale);

    colsum_finish<<<dim3(BS * DKDIM / 256), 256, 0, stream>>>(rpart, rinv);

    vprime_kernel<<<dim3(BS * SEQ * DKDIM / 1024), 256, 0, stream>>>(v, rinv, vp);

    gemm2_av_pipe<<<dim3(DKDIM / 128, SEQ / 256, BS), 512, 0, stream>>>(vp, E, out);
}